// Round 5
// baseline (168.028 us; speedup 1.0000x reference)
//
#include <hip/hip_runtime.h>
#include <hip/hip_bf16.h>

// Problem constants (B=1, N=2048, D=1024, H=16, HD=64; NO=74 offsets)
#define SEQ_N 2048
#define DIM   1024
#define NHEAD 16
#define HDIM  64
#define LDQ   4096   // qkvg row stride: [q | k | v | gatepre]
#define NOFF  74     // 65 dense (0..64) + 9 dyadic
#define NDENSE 65
#define NJ    224    // 80 dense rows + 9*16 dyadic rows
#define NT    16     // n-rows per attention block
#define PST   232    // Pd row stride (padded, 16B-aligned)
#define TST   232    // VbufT row stride (padded, 16B-aligned, 4-way-max banks)
#define QST   88     // Qbuf row stride (16B-aligned)

typedef __attribute__((ext_vector_type(8))) __bf16 bv8;
typedef __attribute__((ext_vector_type(4))) __bf16 bv4;
typedef __attribute__((ext_vector_type(4))) float  f32x4;

typedef __attribute__((address_space(3))) void as3_void;
typedef __attribute__((address_space(1))) void as1_void;

// async global->LDS 16B copy. LDS dest must be wave-uniform base + lane*16.
__device__ __forceinline__ void async16(const void* g, void* l) {
  __builtin_amdgcn_global_load_lds((as1_void*)(unsigned long long)g,
                                   (as3_void*)l, 16, 0, 0);
}

// ---------------------------------------------------------------------------
// fp32 -> bf16 convert, all 4 tensors in one launch (dst regions contiguous).
// ---------------------------------------------------------------------------
#define E1 (SEQ_N * DIM)            // x
#define E2 (E1 + 3 * DIM * DIM)     // + Wqkv
#define E3 (E2 + DIM * DIM)         // + Wgate
#define E4 (E3 + DIM * DIM)         // + Wout
__global__ __launch_bounds__(256) void cvt_all(
    const float* __restrict__ x, const float* __restrict__ wqkv,
    const float* __restrict__ wgate, const float* __restrict__ wout,
    __bf16* __restrict__ dst) {
  long i = ((long)blockIdx.x * 256 + threadIdx.x) * 4;
  if (i >= E4) return;
  const float* s; long o;
  if (i < E1)      { s = x;     o = i; }
  else if (i < E2) { s = wqkv;  o = i - E1; }
  else if (i < E3) { s = wgate; o = i - E2; }
  else             { s = wout;  o = i - E3; }
  float4 v = *(const float4*)(s + o);
  bv4 ov;
  ov[0] = (__bf16)v.x; ov[1] = (__bf16)v.y; ov[2] = (__bf16)v.z; ov[3] = (__bf16)v.w;
  *(bv4*)(dst + i) = ov;
}

// ---------------------------------------------------------------------------
// GEMM: C[M x Nout] = A[M x K] * B[Nout x K]^T + bias (fp32), bf16 in, fp32
// accum, OutT out. Template BN_: 128 or 64. BM=128, BK=32. m97 structure.
// XCD-aware swizzle: each XCD owns a contiguous N-slice so its B-slice stays
// L2-resident (gridDim.x must be a multiple of 8).
// ---------------------------------------------------------------------------
#define BM 128
#define BK 32

template <int BN_, typename OutT>
__global__ __launch_bounds__(256) void gemm_bt(
    const __bf16* __restrict__ A, const __bf16* __restrict__ B1,
    const __bf16* __restrict__ B2, const float* __restrict__ bias1,
    const float* __restrict__ bias2, int Nsplit,
    OutT* __restrict__ C, int ldc, int K) {
  __shared__ __attribute__((aligned(16))) __bf16 Asm[BM * BK];
  __shared__ __attribute__((aligned(16))) __bf16 Bsm[BN_ * BK];
  constexpr int NJT = BN_ / 32;           // j-tiles per wave
  constexpr int CA = BM * BK / 8;         // A 16B-chunks
  constexpr int CB = BN_ * BK / 8;        // B 16B-chunks

  const int tid  = threadIdx.x;
  const int lane = tid & 63;
  const int wave = tid >> 6;
  const int wr = wave >> 1, wc = wave & 1;
  const int fr = lane & 15, fq = lane >> 4;

  // XCD swizzle (heuristic: consecutive blocks round-robin across 8 XCDs)
  int flat = blockIdx.y * gridDim.x + blockIdx.x;
  int nch  = gridDim.x >> 3;
  int xcd  = flat & 7, loc = flat >> 3;
  const int bn0 = (xcd * nch + (loc % nch)) * BN_;
  const int bm0 = (loc / nch) * BM;

  const __bf16* Bp;
  const float* biasp;
  if (bn0 < Nsplit) { Bp = B1 + (size_t)bn0 * K;            biasp = bias1 + bn0; }
  else              { Bp = B2 + (size_t)(bn0 - Nsplit) * K; biasp = bias2 + (bn0 - Nsplit); }
  const __bf16* Ap = A + (size_t)bm0 * K;

  f32x4 acc[4][NJT] = {};

  for (int kt = 0; kt < K; kt += BK) {
    __syncthreads();
#pragma unroll
    for (int c0 = 0; c0 < CA + CB; c0 += 256) {
      int c = c0 + tid;
      if (c < CA) {
        int rr = c >> 2, qq = c & 3;
        async16(Ap + (size_t)rr * K + kt + qq * 8, Asm + c * 8);
      } else {
        int cb = c - CA;
        int rr = cb >> 2, qq = cb & 3;
        async16(Bp + (size_t)rr * K + kt + qq * 8, Bsm + cb * 8);
      }
    }
    __syncthreads();

    bv8 af[4], bfr[NJT];
#pragma unroll
    for (int i = 0; i < 4; ++i)
      af[i] = *(const bv8*)(Asm + (wr * 64 + i * 16 + fr) * BK + fq * 8);
#pragma unroll
    for (int j = 0; j < NJT; ++j)
      bfr[j] = *(const bv8*)(Bsm + (wc * (BN_ / 2) + j * 16 + fr) * BK + fq * 8);
#pragma unroll
    for (int i = 0; i < 4; ++i)
#pragma unroll
      for (int j = 0; j < NJT; ++j)
        acc[i][j] = __builtin_amdgcn_mfma_f32_16x16x32_bf16(af[i], bfr[j], acc[i][j], 0, 0, 0);
  }

#pragma unroll
  for (int i = 0; i < 4; ++i) {
#pragma unroll
    for (int j = 0; j < NJT; ++j) {
      int ccol = wc * (BN_ / 2) + j * 16 + fr;
      float b = biasp[ccol];
#pragma unroll
      for (int r = 0; r < 4; ++r) {
        int row = bm0 + wr * 64 + i * 16 + fq * 4 + r;
        C[(size_t)row * ldc + bn0 + ccol] = (OutT)(acc[i][j][r] + b);
      }
    }
  }
}

// ---------------------------------------------------------------------------
// MFMA-tile attention + gate. One 256-thread block per (16-row n-tile, head).
// K rows j: 0..79 dense (g = n0-64+j), 80+16s+r dyadic (g = n0-off[65+s]+r).
// V staged TRANSPOSED (VbufT[d][j]) via register path so PV B-fragments are
// contiguous ds_read_b128. Scores = Q @ Kbuf^T via MFMA -> banded Sbuf,
// softmax -> banded P (bf16) in Pd, PV = Pd @ V via MFMA, epilogue fuses
// 1/l and sigmoid gate.
// ---------------------------------------------------------------------------
__global__ __launch_bounds__(256) void attn_mfma(
    const __bf16* __restrict__ qkv,      // [SEQ_N x LDQ]
    const float* __restrict__ pos_bias,  // [NOFF x NHEAD]
    const int* __restrict__ offsets,     // [NOFF]
    __bf16* __restrict__ fg) {
  const int n0 = (blockIdx.x >> 4) * NT;
  const int h  = blockIdx.x & 15;
  const int tid = threadIdx.x;
  const int lane = tid & 63;
  const int w = tid >> 6;
  const int fr = lane & 15, fq = lane >> 4;

  __shared__ __attribute__((aligned(16))) __bf16 Kbuf[NJ * HDIM];     // 28672 B
  __shared__ __attribute__((aligned(16))) __bf16 VbufT[HDIM * TST];   // 29696 B
  __shared__ __attribute__((aligned(16))) __bf16 Qbuf[NT * QST];      // 2816 B
  __shared__ __attribute__((aligned(16))) float  Sbuf[NT][80];        // 5120 B
  __shared__ __attribute__((aligned(16))) __bf16 Pd[NT * PST];        // 7424 B
  __shared__ float inv_l[NT];

  // --- Phase 0: stage Q, zero Pd, async-stage K, reg-transpose V ---
  if (tid < 128) {
    int ni = tid >> 3, ch = tid & 7;
    bv8 q = *(const bv8*)(qkv + (size_t)(n0 + ni) * LDQ + h * HDIM + ch * 8);
    *(bv8*)(Qbuf + ni * QST + ch * 8) = q;
  }
#pragma unroll
  for (int c0 = 0; c0 < NT * PST / 8; c0 += 256) {
    int c = c0 + tid;
    if (c < NT * PST / 8) *(uint4*)(Pd + c * 8) = make_uint4(0, 0, 0, 0);
  }
  // K: async16, 32 rows per iteration (8 lanes x 16B per row)
  {
    int ch = lane & 7;
#pragma unroll
    for (int it = 0; it < 7; ++it) {
      int jbase = it * 32 + w * 8;
      int j = jbase + (lane >> 3);
      int g;
      if (j < 80) g = n0 - 64 + j;
      else { int jj = j - 80; g = n0 - offsets[NDENSE + (jj >> 4)] + (jj & 15); }
      if (g < 0) g = 0;   // clamp; masked later
      async16(qkv + (size_t)g * LDQ + DIM + h * HDIM + ch * 8,
              Kbuf + jbase * HDIM + lane * 8);
    }
  }
  // V: row-pair register loads -> packed b32 writes into transposed layout.
  // a = tid>>5 selects d-chunk (8 dims), p = tid&31 selects row-pair.
  {
    int a = tid >> 5, p = tid & 31;
#pragma unroll
    for (int it = 0; it < 4; ++it) {
      int pj = it * 32 + p;
      if (pj < NJ / 2) {
        int j0 = pj * 2;
        int g0;
        if (j0 < 80) g0 = n0 - 64 + j0;
        else { int jj = j0 - 80; g0 = n0 - offsets[NDENSE + (jj >> 4)] + (jj & 15); }
        int g1 = g0 + 1;
        if (g0 < 0) g0 = 0;
        if (g1 < 0) g1 = 0;
        bv8 v0 = *(const bv8*)(qkv + (size_t)g0 * LDQ + 2 * DIM + h * HDIM + a * 8);
        bv8 v1 = *(const bv8*)(qkv + (size_t)g1 * LDQ + 2 * DIM + h * HDIM + a * 8);
        const unsigned short* u0 = (const unsigned short*)&v0;
        const unsigned short* u1 = (const unsigned short*)&v1;
#pragma unroll
        for (int i = 0; i < 8; ++i) {
          unsigned pk = (unsigned)u0[i] | ((unsigned)u1[i] << 16);
          *(unsigned*)(VbufT + (a * 8 + i) * TST + j0) = pk;
        }
      }
    }
  }
  __syncthreads();

  // --- Phase 1: scores via MFMA, scatter banded entries to Sbuf ---
  for (int jb = w; jb < 14; jb += 4) {
    f32x4 acc = {};
#pragma unroll
    for (int kk = 0; kk < 2; ++kk) {
      bv8 a = *(const bv8*)(Qbuf + fr * QST + kk * 32 + fq * 8);
      bv8 b = *(const bv8*)(Kbuf + (jb * 16 + fr) * HDIM + kk * 32 + fq * 8);
      acc = __builtin_amdgcn_mfma_f32_16x16x32_bf16(a, b, acc, 0, 0, 0);
    }
    int j = jb * 16 + fr;           // Kbuf row this lane's column maps to
    if (jb < 5) {                   // dense region
      bool gvalid = (n0 - 64 + j) >= 0;
#pragma unroll
      for (int r = 0; r < 4; ++r) {
        int ni = fq * 4 + r;
        int o = ni + 64 - j;
        if (o >= 0 && o < NDENSE)
          Sbuf[ni][o] = gvalid ? acc[r] : -3.0e38f;
      }
    } else {                        // dyadic: only diagonal entries used
      int jj = j - 80;
      int s = jj >> 4, tni = jj & 15;
      int r = tni - fq * 4;
      if (r >= 0 && r < 4) {
        bool gvalid = (n0 + tni - offsets[NDENSE + s]) >= 0;
        Sbuf[tni][NDENSE + s] = gvalid ? acc[r] : -3.0e38f;
      }
    }
  }
  __syncthreads();

  // --- Phase 2: softmax (16 threads per row), banded P -> Pd (bf16) ---
  {
    int t = tid & 15, ni = tid >> 4;
    float sc5[5];
    float m = -3.0e38f;
#pragma unroll
    for (int k = 0; k < 5; ++k) {
      int o = t + k * 16;
      float v = -3.0e38f;
      if (o < NOFF) {
        float raw = Sbuf[ni][o];
        if (raw > -1.0e38f) v = raw * 0.125f + pos_bias[o * NHEAD + h];
      }
      sc5[k] = v;
      m = fmaxf(m, v);
    }
#pragma unroll
    for (int d = 1; d < 16; d <<= 1) m = fmaxf(m, __shfl_xor(m, d));
    float sum = 0.f;
#pragma unroll
    for (int k = 0; k < 5; ++k) {
      int o = t + k * 16;
      if (o < NOFF && sc5[k] > -1.0e38f) {
        float e = __expf(sc5[k] - m);
        sum += e;
        int j = (o < NDENSE) ? (ni + 64 - o) : (80 + (o - NDENSE) * 16 + ni);
        Pd[ni * PST + j] = (__bf16)e;
      }
    }
#pragma unroll
    for (int d = 1; d < 16; d <<= 1) sum += __shfl_xor(sum, d);
    if (t == 0) inv_l[ni] = 1.f / sum;
  }
  __syncthreads();

  // --- Phase 3: PV via MFMA (each wave one 16-col d-tile) + gate epilogue ---
  {
    const int db = w;
    f32x4 acc = {};
#pragma unroll
    for (int kt = 0; kt < 7; ++kt) {
      bv8 a = *(const bv8*)(Pd + fr * PST + kt * 32 + fq * 8);
      bv8 b = *(const bv8*)(VbufT + (db * 16 + fr) * TST + kt * 32 + fq * 8);
      acc = __builtin_amdgcn_mfma_f32_16x16x32_bf16(a, b, acc, 0, 0, 0);
    }
    int d = db * 16 + fr;
#pragma unroll
    for (int r = 0; r < 4; ++r) {
      int ni = fq * 4 + r;
      float o = acc[r] * inv_l[ni];
      float gp = (float)qkv[(size_t)(n0 + ni) * LDQ + 3 * DIM + h * HDIM + d];
      float gate = 1.f / (1.f + __expf(-gp));
      fg[(size_t)(n0 + ni) * DIM + h * HDIM + d] = (__bf16)(o * gate);
    }
  }
}

// ---------------------------------------------------------------------------
extern "C" void kernel_launch(void* const* d_in, const int* in_sizes, int n_in,
                              void* d_out, int out_size, void* d_ws, size_t ws_size,
                              hipStream_t stream) {
  const float* x        = (const float*)d_in[0];
  const float* Wqkv     = (const float*)d_in[1];
  const float* bqkv     = (const float*)d_in[2];
  const float* Wgate    = (const float*)d_in[3];
  const float* bgate    = (const float*)d_in[4];
  const float* Wout     = (const float*)d_in[5];
  const float* bout     = (const float*)d_in[6];
  const float* pos_bias = (const float*)d_in[7];
  const int*   offsets  = (const int*)d_in[8];
  float* out = (float*)d_out;

  // workspace layout (bf16), cvt dst regions contiguous in this order
  __bf16* xb       = (__bf16*)d_ws;                               // 2048x1024
  __bf16* Wqkvb    = xb    + (size_t)SEQ_N * DIM;                 // 3072x1024
  __bf16* Wgateb   = Wqkvb + (size_t)3 * DIM * DIM;               // 1024x1024
  __bf16* Woutb    = Wgateb + (size_t)DIM * DIM;                  // 1024x1024
  __bf16* qkvg     = Woutb + (size_t)DIM * DIM;                   // 2048x4096
  __bf16* flatgate = qkvg + (size_t)SEQ_N * LDQ;                  // 2048x1024

  // 0) fp32 -> bf16 (single launch)
  cvt_all<<<dim3(E4 / 1024), dim3(256), 0, stream>>>(x, Wqkv, Wgate, Wout, xb);

  // 1) [qkv | gate_pre] = x @ [Wqkv;Wgate]^T + [bqkv;bgate]  -> bf16 qkvg
  gemm_bt<128, __bf16><<<dim3(LDQ / 128, SEQ_N / BM), dim3(256), 0, stream>>>(
      xb, Wqkvb, Wgateb, bqkv, bgate, 3 * DIM, qkvg, LDQ, DIM);

  // 2) attention + sigmoid-gate fuse -> flatgate (bf16)
  attn_mfma<<<dim3((SEQ_N / NT) * NHEAD), dim3(256), 0, stream>>>(
      qkvg, pos_bias, offsets, flatgate);

  // 3) out = flatgate @ Wout^T + bout  -> fp32 d_out (BN=64: 256 blocks)
  gemm_bt<64, float><<<dim3(DIM / 64, SEQ_N / BM), dim3(256), 0, stream>>>(
      flatgate, Woutb, Woutb, bout, bout, 1 << 30, out, DIM, DIM);
}

// Round 6
// 159.116 us; speedup vs baseline: 1.0560x; 1.0560x over previous
//
#include <hip/hip_runtime.h>
#include <hip/hip_bf16.h>

// Problem constants (B=1, N=2048, D=1024, H=16, HD=64; NO=74 offsets)
#define SEQ_N 2048
#define DIM   1024
#define NHEAD 16
#define HDIM  64
#define LDQ   4096   // qkvg row stride: [q | k | v | gatepre]
#define NOFF  74     // 65 dense (0..64) + 9 dyadic
#define NDENSE 65
#define NJ    224    // 80 dense rows + 9*16 dyadic rows
#define NT    16     // n-rows per attention block
#define PST   232    // Pd row stride (padded, 16B-aligned)
#define QST   88     // Qbuf row stride (16B-aligned)

typedef __attribute__((ext_vector_type(8))) __bf16 bv8;
typedef __attribute__((ext_vector_type(4))) __bf16 bv4;
typedef __attribute__((ext_vector_type(4))) float  f32x4;

typedef __attribute__((address_space(3))) void as3_void;
typedef __attribute__((address_space(1))) void as1_void;

// async global->LDS 16B copy. LDS dest must be wave-uniform base + lane*16.
__device__ __forceinline__ void async16(const void* g, void* l) {
  __builtin_amdgcn_global_load_lds((as1_void*)(unsigned long long)g,
                                   (as3_void*)l, 16, 0, 0);
}

// ---------------------------------------------------------------------------
// fp32 -> bf16 convert, all 4 tensors in one launch (dst regions contiguous).
// ---------------------------------------------------------------------------
#define E1 (SEQ_N * DIM)            // x
#define E2 (E1 + 3 * DIM * DIM)     // + Wqkv
#define E3 (E2 + DIM * DIM)         // + Wgate
#define E4 (E3 + DIM * DIM)         // + Wout
__global__ __launch_bounds__(256) void cvt_all(
    const float* __restrict__ x, const float* __restrict__ wqkv,
    const float* __restrict__ wgate, const float* __restrict__ wout,
    __bf16* __restrict__ dst) {
  long i = ((long)blockIdx.x * 256 + threadIdx.x) * 4;
  if (i >= E4) return;
  const float* s; long o;
  if (i < E1)      { s = x;     o = i; }
  else if (i < E2) { s = wqkv;  o = i - E1; }
  else if (i < E3) { s = wgate; o = i - E2; }
  else             { s = wout;  o = i - E3; }
  float4 v = *(const float4*)(s + o);
  bv4 ov;
  ov[0] = (__bf16)v.x; ov[1] = (__bf16)v.y; ov[2] = (__bf16)v.z; ov[3] = (__bf16)v.w;
  *(bv4*)(dst + i) = ov;
}

// ---------------------------------------------------------------------------
// GEMM (128xBN_ tile): C[M x Nout] = A[M x K] * B[Nout x K]^T + bias, bf16 in,
// fp32 accum, OutT out. B split at col Nsplit. BM=128, BK=32. m97 structure.
// No XCD swizzle (R5 showed it regressed).
// ---------------------------------------------------------------------------
#define BM 128
#define BK 32

template <int BN_, typename OutT>
__global__ __launch_bounds__(256) void gemm_bt(
    const __bf16* __restrict__ A, const __bf16* __restrict__ B1,
    const __bf16* __restrict__ B2, const float* __restrict__ bias1,
    const float* __restrict__ bias2, int Nsplit,
    OutT* __restrict__ C, int ldc, int K) {
  __shared__ __attribute__((aligned(16))) __bf16 Asm[BM * BK];
  __shared__ __attribute__((aligned(16))) __bf16 Bsm[BN_ * BK];
  constexpr int NJT = BN_ / 32;           // j-tiles per wave
  constexpr int CA = BM * BK / 8;         // A 16B-chunks
  constexpr int CB = BN_ * BK / 8;        // B 16B-chunks

  const int tid  = threadIdx.x;
  const int lane = tid & 63;
  const int wave = tid >> 6;
  const int wr = wave >> 1, wc = wave & 1;
  const int fr = lane & 15, fq = lane >> 4;

  const int bn0 = blockIdx.x * BN_;
  const int bm0 = blockIdx.y * BM;

  const __bf16* Bp;
  const float* biasp;
  if (bn0 < Nsplit) { Bp = B1 + (size_t)bn0 * K;            biasp = bias1 + bn0; }
  else              { Bp = B2 + (size_t)(bn0 - Nsplit) * K; biasp = bias2 + (bn0 - Nsplit); }
  const __bf16* Ap = A + (size_t)bm0 * K;

  f32x4 acc[4][NJT] = {};

  for (int kt = 0; kt < K; kt += BK) {
    __syncthreads();
#pragma unroll
    for (int c0 = 0; c0 < CA + CB; c0 += 256) {
      int c = c0 + tid;
      if (c < CA) {
        int rr = c >> 2, qq = c & 3;
        async16(Ap + (size_t)rr * K + kt + qq * 8, Asm + c * 8);
      } else {
        int cb = c - CA;
        int rr = cb >> 2, qq = cb & 3;
        async16(Bp + (size_t)rr * K + kt + qq * 8, Bsm + cb * 8);
      }
    }
    __syncthreads();

    bv8 af[4], bfr[NJT];
#pragma unroll
    for (int i = 0; i < 4; ++i)
      af[i] = *(const bv8*)(Asm + (wr * 64 + i * 16 + fr) * BK + fq * 8);
#pragma unroll
    for (int j = 0; j < NJT; ++j)
      bfr[j] = *(const bv8*)(Bsm + (wc * (BN_ / 2) + j * 16 + fr) * BK + fq * 8);
#pragma unroll
    for (int i = 0; i < 4; ++i)
#pragma unroll
      for (int j = 0; j < NJT; ++j)
        acc[i][j] = __builtin_amdgcn_mfma_f32_16x16x32_bf16(af[i], bfr[j], acc[i][j], 0, 0, 0);
  }

#pragma unroll
  for (int i = 0; i < 4; ++i) {
#pragma unroll
    for (int j = 0; j < NJT; ++j) {
      int ccol = wc * (BN_ / 2) + j * 16 + fr;
      float b = biasp[ccol];
#pragma unroll
      for (int r = 0; r < 4; ++r) {
        int row = bm0 + wr * 64 + i * 16 + fq * 4 + r;
        C[(size_t)row * ldc + bn0 + ccol] = (OutT)(acc[i][j][r] + b);
      }
    }
  }
}

// ---------------------------------------------------------------------------
// GEMM 64x64 tile (for gemm3's 2048x1024 shape -> 512 blocks, 2+/CU).
// 4 waves in 2x2; each wave a 32x32 tile via 2x2 of 16x16x32 MFMA. BK=32.
// ---------------------------------------------------------------------------
template <typename OutT>
__global__ __launch_bounds__(256) void gemm_bt64(
    const __bf16* __restrict__ A, const __bf16* __restrict__ B,
    const float* __restrict__ bias, OutT* __restrict__ C, int ldc, int K) {
  __shared__ __attribute__((aligned(16))) __bf16 Asm[64 * BK];  // 4 KB
  __shared__ __attribute__((aligned(16))) __bf16 Bsm[64 * BK];  // 4 KB

  const int tid  = threadIdx.x;
  const int lane = tid & 63;
  const int wave = tid >> 6;
  const int wr = wave >> 1, wc = wave & 1;
  const int fr = lane & 15, fq = lane >> 4;

  const int bn0 = blockIdx.x * 64;
  const int bm0 = blockIdx.y * 64;

  const __bf16* Ap = A + (size_t)bm0 * K;
  const __bf16* Bp = B + (size_t)bn0 * K;
  const float* biasp = bias + bn0;

  f32x4 acc[2][2] = {};

  // staging: 256 chunks A + 256 chunks B; thread t does chunk t of each.
  const int rr = tid >> 2, qq = tid & 3;

  for (int kt = 0; kt < K; kt += BK) {
    __syncthreads();
    async16(Ap + (size_t)rr * K + kt + qq * 8, Asm + tid * 8);
    async16(Bp + (size_t)rr * K + kt + qq * 8, Bsm + tid * 8);
    __syncthreads();

    bv8 af[2], bfr[2];
#pragma unroll
    for (int i = 0; i < 2; ++i)
      af[i] = *(const bv8*)(Asm + (wr * 32 + i * 16 + fr) * BK + fq * 8);
#pragma unroll
    for (int j = 0; j < 2; ++j)
      bfr[j] = *(const bv8*)(Bsm + (wc * 32 + j * 16 + fr) * BK + fq * 8);
#pragma unroll
    for (int i = 0; i < 2; ++i)
#pragma unroll
      for (int j = 0; j < 2; ++j)
        acc[i][j] = __builtin_amdgcn_mfma_f32_16x16x32_bf16(af[i], bfr[j], acc[i][j], 0, 0, 0);
  }

#pragma unroll
  for (int i = 0; i < 2; ++i) {
#pragma unroll
    for (int j = 0; j < 2; ++j) {
      int ccol = wc * 32 + j * 16 + fr;
      float b = biasp[ccol];
#pragma unroll
      for (int r = 0; r < 4; ++r) {
        int row = bm0 + wr * 32 + i * 16 + fq * 4 + r;
        C[(size_t)row * ldc + bn0 + ccol] = (OutT)(acc[i][j][r] + b);
      }
    }
  }
}

// ---------------------------------------------------------------------------
// MFMA-tile attention + gate (round-4 version, verified fastest so far).
// One 256-thread block per (16-row n-tile, head).
// ---------------------------------------------------------------------------
__global__ __launch_bounds__(256) void attn_mfma(
    const __bf16* __restrict__ qkv,      // [SEQ_N x LDQ]
    const float* __restrict__ pos_bias,  // [NOFF x NHEAD]
    const int* __restrict__ offsets,     // [NOFF]
    __bf16* __restrict__ fg) {
  const int n0 = (blockIdx.x >> 4) * NT;
  const int h  = blockIdx.x & 15;
  const int tid = threadIdx.x;
  const int lane = tid & 63;
  const int w = tid >> 6;
  const int fr = lane & 15, fq = lane >> 4;

  __shared__ __attribute__((aligned(16))) __bf16 Kbuf[NJ * HDIM];   // 28672 B
  __shared__ __attribute__((aligned(16))) __bf16 Vbuf[NJ * HDIM];   // 28672 B
  __shared__ __attribute__((aligned(16))) __bf16 Qbuf[NT * QST];    // 2816 B
  __shared__ __attribute__((aligned(16))) float  Sbuf[NT][80];      // 5120 B
  __shared__ __attribute__((aligned(16))) __bf16 Pd[NT * PST];      // 7424 B
  __shared__ float inv_l[NT];

  // --- Phase 0: stage Q, zero Pd, async-stage K/V ---
  if (tid < 128) {
    int ni = tid >> 3, ch = tid & 7;
    bv8 q = *(const bv8*)(qkv + (size_t)(n0 + ni) * LDQ + h * HDIM + ch * 8);
    *(bv8*)(Qbuf + ni * QST + ch * 8) = q;
  }
#pragma unroll
  for (int c0 = 0; c0 < NT * PST / 8; c0 += 256) {
    int c = c0 + tid;
    if (c < NT * PST / 8) *(uint4*)(Pd + c * 8) = make_uint4(0, 0, 0, 0);
  }
  {
    int ch = lane & 7;
#pragma unroll
    for (int it = 0; it < 7; ++it) {
      int jbase = it * 32 + w * 8;
      int j = jbase + (lane >> 3);
      int g;
      if (j < 80) g = n0 - 64 + j;
      else { int jj = j - 80; g = n0 - offsets[NDENSE + (jj >> 4)] + (jj & 15); }
      if (g < 0) g = 0;   // clamp; masked later
      const __bf16* kg = qkv + (size_t)g * LDQ + DIM + h * HDIM + ch * 8;
      async16(kg, Kbuf + jbase * HDIM + lane * 8);
      async16(kg + DIM, Vbuf + jbase * HDIM + lane * 8);
    }
  }
  __syncthreads();

  // --- Phase 1: scores via MFMA, scatter banded entries to Sbuf ---
  for (int jb = w; jb < 14; jb += 4) {
    f32x4 acc = {};
#pragma unroll
    for (int kk = 0; kk < 2; ++kk) {
      bv8 a = *(const bv8*)(Qbuf + fr * QST + kk * 32 + fq * 8);
      bv8 b = *(const bv8*)(Kbuf + (jb * 16 + fr) * HDIM + kk * 32 + fq * 8);
      acc = __builtin_amdgcn_mfma_f32_16x16x32_bf16(a, b, acc, 0, 0, 0);
    }
    int j = jb * 16 + fr;           // Kbuf row this lane's column maps to
    if (jb < 5) {                   // dense region
      bool gvalid = (n0 - 64 + j) >= 0;
#pragma unroll
      for (int r = 0; r < 4; ++r) {
        int ni = fq * 4 + r;
        int o = ni + 64 - j;
        if (o >= 0 && o < NDENSE)
          Sbuf[ni][o] = gvalid ? acc[r] : -3.0e38f;
      }
    } else {                        // dyadic: only diagonal entries used
      int jj = j - 80;
      int s = jj >> 4, tni = jj & 15;
      int r = tni - fq * 4;
      if (r >= 0 && r < 4) {
        bool gvalid = (n0 + tni - offsets[NDENSE + s]) >= 0;
        Sbuf[tni][NDENSE + s] = gvalid ? acc[r] : -3.0e38f;
      }
    }
  }
  __syncthreads();

  // --- Phase 2: softmax (16 threads per row), banded P -> Pd (bf16) ---
  {
    int t = tid & 15, ni = tid >> 4;
    float sc5[5];
    float m = -3.0e38f;
#pragma unroll
    for (int k = 0; k < 5; ++k) {
      int o = t + k * 16;
      float v = -3.0e38f;
      if (o < NOFF) {
        float raw = Sbuf[ni][o];
        if (raw > -1.0e38f) v = raw * 0.125f + pos_bias[o * NHEAD + h];
      }
      sc5[k] = v;
      m = fmaxf(m, v);
    }
#pragma unroll
    for (int d = 1; d < 16; d <<= 1) m = fmaxf(m, __shfl_xor(m, d));
    float sum = 0.f;
#pragma unroll
    for (int k = 0; k < 5; ++k) {
      int o = t + k * 16;
      if (o < NOFF && sc5[k] > -1.0e38f) {
        float e = __expf(sc5[k] - m);
        sum += e;
        int j = (o < NDENSE) ? (ni + 64 - o) : (80 + (o - NDENSE) * 16 + ni);
        Pd[ni * PST + j] = (__bf16)e;
      }
    }
#pragma unroll
    for (int d = 1; d < 16; d <<= 1) sum += __shfl_xor(sum, d);
    if (t == 0) inv_l[ni] = 1.f / sum;
  }
  __syncthreads();

  // --- Phase 3: PV via MFMA (each wave one 16-col d-tile) + gate epilogue ---
  {
    const int db = w;
    f32x4 acc = {};
#pragma unroll
    for (int kt = 0; kt < 7; ++kt) {
      bv8 a = *(const bv8*)(Pd + fr * PST + kt * 32 + fq * 8);
      bv8 b;
#pragma unroll
      for (int jj = 0; jj < 8; ++jj)
        b[jj] = Vbuf[(kt * 32 + fq * 8 + jj) * HDIM + db * 16 + fr];
      acc = __builtin_amdgcn_mfma_f32_16x16x32_bf16(a, b, acc, 0, 0, 0);
    }
    int d = db * 16 + fr;
#pragma unroll
    for (int r = 0; r < 4; ++r) {
      int ni = fq * 4 + r;
      float o = acc[r] * inv_l[ni];
      float gp = (float)qkv[(size_t)(n0 + ni) * LDQ + 3 * DIM + h * HDIM + d];
      float gate = 1.f / (1.f + __expf(-gp));
      fg[(size_t)(n0 + ni) * DIM + h * HDIM + d] = (__bf16)(o * gate);
    }
  }
}

// ---------------------------------------------------------------------------
extern "C" void kernel_launch(void* const* d_in, const int* in_sizes, int n_in,
                              void* d_out, int out_size, void* d_ws, size_t ws_size,
                              hipStream_t stream) {
  const float* x        = (const float*)d_in[0];
  const float* Wqkv     = (const float*)d_in[1];
  const float* bqkv     = (const float*)d_in[2];
  const float* Wgate    = (const float*)d_in[3];
  const float* bgate    = (const float*)d_in[4];
  const float* Wout     = (const float*)d_in[5];
  const float* bout     = (const float*)d_in[6];
  const float* pos_bias = (const float*)d_in[7];
  const int*   offsets  = (const int*)d_in[8];
  float* out = (float*)d_out;

  // workspace layout (bf16), cvt dst regions contiguous in this order
  __bf16* xb       = (__bf16*)d_ws;                               // 2048x1024
  __bf16* Wqkvb    = xb    + (size_t)SEQ_N * DIM;                 // 3072x1024
  __bf16* Wgateb   = Wqkvb + (size_t)3 * DIM * DIM;               // 1024x1024
  __bf16* Woutb    = Wgateb + (size_t)DIM * DIM;                  // 1024x1024
  __bf16* qkvg     = Woutb + (size_t)DIM * DIM;                   // 2048x4096
  __bf16* flatgate = qkvg + (size_t)SEQ_N * LDQ;                  // 2048x1024

  // 0) fp32 -> bf16 (single launch)
  cvt_all<<<dim3(E4 / 1024), dim3(256), 0, stream>>>(x, Wqkv, Wgate, Wout, xb);

  // 1) [qkv | gate_pre] = x @ [Wqkv;Wgate]^T + [bqkv;bgate]  -> bf16 qkvg
  gemm_bt<128, __bf16><<<dim3(LDQ / 128, SEQ_N / BM), dim3(256), 0, stream>>>(
      xb, Wqkvb, Wgateb, bqkv, bgate, 3 * DIM, qkvg, LDQ, DIM);

  // 2) attention + sigmoid-gate fuse -> flatgate (bf16)
  attn_mfma<<<dim3((SEQ_N / NT) * NHEAD), dim3(256), 0, stream>>>(
      qkvg, pos_bias, offsets, flatgate);

  // 3) out = flatgate @ Wout^T + bout  -> fp32 d_out (64x64 tiles: 512 blocks)
  gemm_bt64<float><<<dim3(DIM / 64, SEQ_N / 64), dim3(256), 0, stream>>>(
      flatgate, Woutb, bout, out, DIM, DIM);
}

// Round 7
// 154.847 us; speedup vs baseline: 1.0851x; 1.0276x over previous
//
#include <hip/hip_runtime.h>
#include <hip/hip_bf16.h>

// Problem constants (B=1, N=2048, D=1024, H=16, HD=64; NO=74 offsets)
#define SEQ_N 2048
#define DIM   1024
#define NHEAD 16
#define HDIM  64
#define LDQ   4096   // qkvg row stride: [q | k | v | gatepre]
#define NOFF  74     // 65 dense (0..64) + 9 dyadic
#define NDENSE 65
#define NJ    224    // 80 dense rows + 9*16 dyadic rows
#define NT    16     // n-rows per attention block
#define PST   232    // Pd row stride (padded, 16B-aligned)
#define QST   88     // Qbuf row stride (16B-aligned)

typedef __attribute__((ext_vector_type(8))) __bf16 bv8;
typedef __attribute__((ext_vector_type(4))) __bf16 bv4;
typedef __attribute__((ext_vector_type(4))) float  f32x4;

typedef __attribute__((address_space(3))) void as3_void;
typedef __attribute__((address_space(1))) void as1_void;

// async global->LDS 16B copy. LDS dest must be wave-uniform base + lane*16.
__device__ __forceinline__ void async16(const void* g, void* l) {
  __builtin_amdgcn_global_load_lds((as1_void*)(unsigned long long)g,
                                   (as3_void*)l, 16, 0, 0);
}

// ---------------------------------------------------------------------------
// fp32 -> bf16 convert, all 4 tensors in one launch (dst regions contiguous).
// ---------------------------------------------------------------------------
#define E1 (SEQ_N * DIM)            // x
#define E2 (E1 + 3 * DIM * DIM)     // + Wqkv
#define E3 (E2 + DIM * DIM)         // + Wgate
#define E4 (E3 + DIM * DIM)         // + Wout
__global__ __launch_bounds__(256) void cvt_all(
    const float* __restrict__ x, const float* __restrict__ wqkv,
    const float* __restrict__ wgate, const float* __restrict__ wout,
    __bf16* __restrict__ dst) {
  long i = ((long)blockIdx.x * 256 + threadIdx.x) * 4;
  if (i >= E4) return;
  const float* s; long o;
  if (i < E1)      { s = x;     o = i; }
  else if (i < E2) { s = wqkv;  o = i - E1; }
  else if (i < E3) { s = wgate; o = i - E2; }
  else             { s = wout;  o = i - E3; }
  float4 v = *(const float4*)(s + o);
  bv4 ov;
  ov[0] = (__bf16)v.x; ov[1] = (__bf16)v.y; ov[2] = (__bf16)v.z; ov[3] = (__bf16)v.w;
  *(bv4*)(dst + i) = ov;
}

// ---------------------------------------------------------------------------
// GEMM (128xBN_ tile, BK=64): C = A[MxK] * B[NoutxK]^T + bias, bf16 in, fp32
// accum, OutT out. B split at col Nsplit. m97 staging (async16 width-16) with
// halved barrier count vs BK=32; LDS 32 KB keeps 3 blocks/CU (VGPR-capped).
// ---------------------------------------------------------------------------
#define BM 128
#define BKG 64

template <int BN_, typename OutT>
__global__ __launch_bounds__(256) void gemm_bt(
    const __bf16* __restrict__ A, const __bf16* __restrict__ B1,
    const __bf16* __restrict__ B2, const float* __restrict__ bias1,
    const float* __restrict__ bias2, int Nsplit,
    OutT* __restrict__ C, int ldc, int K) {
  __shared__ __attribute__((aligned(16))) __bf16 Asm[BM * BKG];
  __shared__ __attribute__((aligned(16))) __bf16 Bsm[BN_ * BKG];
  constexpr int NJT = BN_ / 32;            // j-tiles per wave
  constexpr int CA = BM * BKG / 8;         // A 16B-chunks
  constexpr int CB = BN_ * BKG / 8;        // B 16B-chunks
  constexpr int CPR = BKG / 8;             // chunks per row

  const int tid  = threadIdx.x;
  const int lane = tid & 63;
  const int wave = tid >> 6;
  const int wr = wave >> 1, wc = wave & 1;
  const int fr = lane & 15, fq = lane >> 4;

  const int bn0 = blockIdx.x * BN_;
  const int bm0 = blockIdx.y * BM;

  const __bf16* Bp;
  const float* biasp;
  if (bn0 < Nsplit) { Bp = B1 + (size_t)bn0 * K;            biasp = bias1 + bn0; }
  else              { Bp = B2 + (size_t)(bn0 - Nsplit) * K; biasp = bias2 + (bn0 - Nsplit); }
  const __bf16* Ap = A + (size_t)bm0 * K;

  f32x4 acc[4][NJT] = {};

  for (int kt = 0; kt < K; kt += BKG) {
    __syncthreads();
#pragma unroll
    for (int c0 = 0; c0 < CA + CB; c0 += 256) {
      int c = c0 + tid;
      if (c < CA) {
        int rr = c / CPR, qq = c % CPR;
        async16(Ap + (size_t)rr * K + kt + qq * 8, Asm + c * 8);
      } else {
        int cb = c - CA;
        int rr = cb / CPR, qq = cb % CPR;
        async16(Bp + (size_t)rr * K + kt + qq * 8, Bsm + cb * 8);
      }
    }
    __syncthreads();

#pragma unroll
    for (int kk = 0; kk < BKG / 32; ++kk) {
      bv8 af[4], bfr[NJT];
#pragma unroll
      for (int i = 0; i < 4; ++i)
        af[i] = *(const bv8*)(Asm + (wr * 64 + i * 16 + fr) * BKG + kk * 32 + fq * 8);
#pragma unroll
      for (int j = 0; j < NJT; ++j)
        bfr[j] = *(const bv8*)(Bsm + (wc * (BN_ / 2) + j * 16 + fr) * BKG + kk * 32 + fq * 8);
#pragma unroll
      for (int i = 0; i < 4; ++i)
#pragma unroll
        for (int j = 0; j < NJT; ++j)
          acc[i][j] = __builtin_amdgcn_mfma_f32_16x16x32_bf16(af[i], bfr[j], acc[i][j], 0, 0, 0);
    }
  }

#pragma unroll
  for (int i = 0; i < 4; ++i) {
#pragma unroll
    for (int j = 0; j < NJT; ++j) {
      int ccol = wc * (BN_ / 2) + j * 16 + fr;
      float b = biasp[ccol];
#pragma unroll
      for (int r = 0; r < 4; ++r) {
        int row = bm0 + wr * 64 + i * 16 + fq * 4 + r;
        C[(size_t)row * ldc + bn0 + ccol] = (OutT)(acc[i][j][r] + b);
      }
    }
  }
}

// ---------------------------------------------------------------------------
// GEMM 64x64 tile, BK=64 (gemm3: 512 blocks, low VGPR -> high co-residency).
// 4 waves in 2x2; each wave a 32x32 tile via 2x2 of 16x16x32 MFMA.
// ---------------------------------------------------------------------------
template <typename OutT>
__global__ __launch_bounds__(256) void gemm_bt64(
    const __bf16* __restrict__ A, const __bf16* __restrict__ B,
    const float* __restrict__ bias, OutT* __restrict__ C, int ldc, int K) {
  __shared__ __attribute__((aligned(16))) __bf16 Asm[64 * BKG];  // 8 KB
  __shared__ __attribute__((aligned(16))) __bf16 Bsm[64 * BKG];  // 8 KB

  const int tid  = threadIdx.x;
  const int lane = tid & 63;
  const int wave = tid >> 6;
  const int wr = wave >> 1, wc = wave & 1;
  const int fr = lane & 15, fq = lane >> 4;

  const int bn0 = blockIdx.x * 64;
  const int bm0 = blockIdx.y * 64;

  const __bf16* Ap = A + (size_t)bm0 * K;
  const __bf16* Bp = B + (size_t)bn0 * K;
  const float* biasp = bias + bn0;

  f32x4 acc[2][2] = {};

  // staging: 512 chunks per matrix (64 rows x 8 chunks); 2 per thread each.
  for (int kt = 0; kt < K; kt += BKG) {
    __syncthreads();
#pragma unroll
    for (int c0 = 0; c0 < 512; c0 += 256) {
      int c = c0 + tid;
      int rr = c >> 3, qq = c & 7;
      async16(Ap + (size_t)rr * K + kt + qq * 8, Asm + c * 8);
      async16(Bp + (size_t)rr * K + kt + qq * 8, Bsm + c * 8);
    }
    __syncthreads();

#pragma unroll
    for (int kk = 0; kk < 2; ++kk) {
      bv8 af[2], bfr[2];
#pragma unroll
      for (int i = 0; i < 2; ++i)
        af[i] = *(const bv8*)(Asm + (wr * 32 + i * 16 + fr) * BKG + kk * 32 + fq * 8);
#pragma unroll
      for (int j = 0; j < 2; ++j)
        bfr[j] = *(const bv8*)(Bsm + (wc * 32 + j * 16 + fr) * BKG + kk * 32 + fq * 8);
#pragma unroll
      for (int i = 0; i < 2; ++i)
#pragma unroll
        for (int j = 0; j < 2; ++j)
          acc[i][j] = __builtin_amdgcn_mfma_f32_16x16x32_bf16(af[i], bfr[j], acc[i][j], 0, 0, 0);
    }
  }

#pragma unroll
  for (int i = 0; i < 2; ++i) {
#pragma unroll
    for (int j = 0; j < 2; ++j) {
      int ccol = wc * 32 + j * 16 + fr;
      float b = biasp[ccol];
#pragma unroll
      for (int r = 0; r < 4; ++r) {
        int row = bm0 + wr * 32 + i * 16 + fq * 4 + r;
        C[(size_t)row * ldc + bn0 + ccol] = (OutT)(acc[i][j][r] + b);
      }
    }
  }
}

// ---------------------------------------------------------------------------
// MFMA-tile attention + gate (round-4 version, verified fastest so far).
// One 256-thread block per (16-row n-tile, head).
// ---------------------------------------------------------------------------
__global__ __launch_bounds__(256) void attn_mfma(
    const __bf16* __restrict__ qkv,      // [SEQ_N x LDQ]
    const float* __restrict__ pos_bias,  // [NOFF x NHEAD]
    const int* __restrict__ offsets,     // [NOFF]
    __bf16* __restrict__ fg) {
  const int n0 = (blockIdx.x >> 4) * NT;
  const int h  = blockIdx.x & 15;
  const int tid = threadIdx.x;
  const int lane = tid & 63;
  const int w = tid >> 6;
  const int fr = lane & 15, fq = lane >> 4;

  __shared__ __attribute__((aligned(16))) __bf16 Kbuf[NJ * HDIM];   // 28672 B
  __shared__ __attribute__((aligned(16))) __bf16 Vbuf[NJ * HDIM];   // 28672 B
  __shared__ __attribute__((aligned(16))) __bf16 Qbuf[NT * QST];    // 2816 B
  __shared__ __attribute__((aligned(16))) float  Sbuf[NT][80];      // 5120 B
  __shared__ __attribute__((aligned(16))) __bf16 Pd[NT * PST];      // 7424 B
  __shared__ float inv_l[NT];

  // --- Phase 0: stage Q, zero Pd, async-stage K/V ---
  if (tid < 128) {
    int ni = tid >> 3, ch = tid & 7;
    bv8 q = *(const bv8*)(qkv + (size_t)(n0 + ni) * LDQ + h * HDIM + ch * 8);
    *(bv8*)(Qbuf + ni * QST + ch * 8) = q;
  }
#pragma unroll
  for (int c0 = 0; c0 < NT * PST / 8; c0 += 256) {
    int c = c0 + tid;
    if (c < NT * PST / 8) *(uint4*)(Pd + c * 8) = make_uint4(0, 0, 0, 0);
  }
  {
    int ch = lane & 7;
#pragma unroll
    for (int it = 0; it < 7; ++it) {
      int jbase = it * 32 + w * 8;
      int j = jbase + (lane >> 3);
      int g;
      if (j < 80) g = n0 - 64 + j;
      else { int jj = j - 80; g = n0 - offsets[NDENSE + (jj >> 4)] + (jj & 15); }
      if (g < 0) g = 0;   // clamp; masked later
      const __bf16* kg = qkv + (size_t)g * LDQ + DIM + h * HDIM + ch * 8;
      async16(kg, Kbuf + jbase * HDIM + lane * 8);
      async16(kg + DIM, Vbuf + jbase * HDIM + lane * 8);
    }
  }
  __syncthreads();

  // --- Phase 1: scores via MFMA, scatter banded entries to Sbuf ---
  for (int jb = w; jb < 14; jb += 4) {
    f32x4 acc = {};
#pragma unroll
    for (int kk = 0; kk < 2; ++kk) {
      bv8 a = *(const bv8*)(Qbuf + fr * QST + kk * 32 + fq * 8);
      bv8 b = *(const bv8*)(Kbuf + (jb * 16 + fr) * HDIM + kk * 32 + fq * 8);
      acc = __builtin_amdgcn_mfma_f32_16x16x32_bf16(a, b, acc, 0, 0, 0);
    }
    int j = jb * 16 + fr;           // Kbuf row this lane's column maps to
    if (jb < 5) {                   // dense region
      bool gvalid = (n0 - 64 + j) >= 0;
#pragma unroll
      for (int r = 0; r < 4; ++r) {
        int ni = fq * 4 + r;
        int o = ni + 64 - j;
        if (o >= 0 && o < NDENSE)
          Sbuf[ni][o] = gvalid ? acc[r] : -3.0e38f;
      }
    } else {                        // dyadic: only diagonal entries used
      int jj = j - 80;
      int s = jj >> 4, tni = jj & 15;
      int r = tni - fq * 4;
      if (r >= 0 && r < 4) {
        bool gvalid = (n0 + tni - offsets[NDENSE + s]) >= 0;
        Sbuf[tni][NDENSE + s] = gvalid ? acc[r] : -3.0e38f;
      }
    }
  }
  __syncthreads();

  // --- Phase 2: softmax (16 threads per row), banded P -> Pd (bf16) ---
  {
    int t = tid & 15, ni = tid >> 4;
    float sc5[5];
    float m = -3.0e38f;
#pragma unroll
    for (int k = 0; k < 5; ++k) {
      int o = t + k * 16;
      float v = -3.0e38f;
      if (o < NOFF) {
        float raw = Sbuf[ni][o];
        if (raw > -1.0e38f) v = raw * 0.125f + pos_bias[o * NHEAD + h];
      }
      sc5[k] = v;
      m = fmaxf(m, v);
    }
#pragma unroll
    for (int d = 1; d < 16; d <<= 1) m = fmaxf(m, __shfl_xor(m, d));
    float sum = 0.f;
#pragma unroll
    for (int k = 0; k < 5; ++k) {
      int o = t + k * 16;
      if (o < NOFF && sc5[k] > -1.0e38f) {
        float e = __expf(sc5[k] - m);
        sum += e;
        int j = (o < NDENSE) ? (ni + 64 - o) : (80 + (o - NDENSE) * 16 + ni);
        Pd[ni * PST + j] = (__bf16)e;
      }
    }
#pragma unroll
    for (int d = 1; d < 16; d <<= 1) sum += __shfl_xor(sum, d);
    if (t == 0) inv_l[ni] = 1.f / sum;
  }
  __syncthreads();

  // --- Phase 3: PV via MFMA (each wave one 16-col d-tile) + gate epilogue ---
  {
    const int db = w;
    f32x4 acc = {};
#pragma unroll
    for (int kt = 0; kt < 7; ++kt) {
      bv8 a = *(const bv8*)(Pd + fr * PST + kt * 32 + fq * 8);
      bv8 b;
#pragma unroll
      for (int jj = 0; jj < 8; ++jj)
        b[jj] = Vbuf[(kt * 32 + fq * 8 + jj) * HDIM + db * 16 + fr];
      acc = __builtin_amdgcn_mfma_f32_16x16x32_bf16(a, b, acc, 0, 0, 0);
    }
    int d = db * 16 + fr;
#pragma unroll
    for (int r = 0; r < 4; ++r) {
      int ni = fq * 4 + r;
      float o = acc[r] * inv_l[ni];
      float gp = (float)qkv[(size_t)(n0 + ni) * LDQ + 3 * DIM + h * HDIM + d];
      float gate = 1.f / (1.f + __expf(-gp));
      fg[(size_t)(n0 + ni) * DIM + h * HDIM + d] = (__bf16)(o * gate);
    }
  }
}

// ---------------------------------------------------------------------------
extern "C" void kernel_launch(void* const* d_in, const int* in_sizes, int n_in,
                              void* d_out, int out_size, void* d_ws, size_t ws_size,
                              hipStream_t stream) {
  const float* x        = (const float*)d_in[0];
  const float* Wqkv     = (const float*)d_in[1];
  const float* bqkv     = (const float*)d_in[2];
  const float* Wgate    = (const float*)d_in[3];
  const float* bgate    = (const float*)d_in[4];
  const float* Wout     = (const float*)d_in[5];
  const float* bout     = (const float*)d_in[6];
  const float* pos_bias = (const float*)d_in[7];
  const int*   offsets  = (const int*)d_in[8];
  float* out = (float*)d_out;

  // workspace layout (bf16), cvt dst regions contiguous in this order
  __bf16* xb       = (__bf16*)d_ws;                               // 2048x1024
  __bf16* Wqkvb    = xb    + (size_t)SEQ_N * DIM;                 // 3072x1024
  __bf16* Wgateb   = Wqkvb + (size_t)3 * DIM * DIM;               // 1024x1024
  __bf16* Woutb    = Wgateb + (size_t)DIM * DIM;                  // 1024x1024
  __bf16* qkvg     = Woutb + (size_t)DIM * DIM;                   // 2048x4096
  __bf16* flatgate = qkvg + (size_t)SEQ_N * LDQ;                  // 2048x1024

  // 0) fp32 -> bf16 (single launch)
  cvt_all<<<dim3(E4 / 1024), dim3(256), 0, stream>>>(x, Wqkv, Wgate, Wout, xb);

  // 1) [qkv | gate_pre] = x @ [Wqkv;Wgate]^T + [bqkv;bgate]  -> bf16 qkvg
  gemm_bt<128, __bf16><<<dim3(LDQ / 128, SEQ_N / BM), dim3(256), 0, stream>>>(
      xb, Wqkvb, Wgateb, bqkv, bgate, 3 * DIM, qkvg, LDQ, DIM);

  // 2) attention + sigmoid-gate fuse -> flatgate (bf16)
  attn_mfma<<<dim3((SEQ_N / NT) * NHEAD), dim3(256), 0, stream>>>(
      qkvg, pos_bias, offsets, flatgate);

  // 3) out = flatgate @ Wout^T + bout  -> fp32 d_out (64x64 tiles: 512 blocks)
  gemm_bt64<float><<<dim3(DIM / 64, SEQ_N / 64), dim3(256), 0, stream>>>(
      flatgate, Woutb, bout, out, DIM, DIM);
}